// Round 14
// baseline (115.633 us; speedup 1.0000x reference)
//
#include <hip/hip_runtime.h>

// ---------------------------------------------------------------------------
// PromptSelector — collapsed algebra, 9 launches.
//   scores[b,h,j] = rden_j*(dot(ga*x_j, wk[:,h]) - mean_j*Sgw[h]) + CgbC[h]
//   w_j = exp(s_j)*rden_j  (unnormalized; division deferred to o0_k:
//        u = ga*(Σ w x − c1raw)/Z + gb, Z = Σ e, c1raw = Σ w*mean)
// Round 14: ln_scores + upart merged into ONE X pass (score_upart). The
// unnormalized-w algebra (R12) removed the cross-row softmax dependency, so a
// block can score row j and immediately accumulate w_j*x_j while x_j is in
// registers. X traffic 50->25 MB; sc/stats buffers deleted; one fewer gap.
// Rank-on-logits head (R13) and last-block decide (R12) kept.
// ---------------------------------------------------------------------------

#define OUT_CLS_OFF 614400   // 8*100*768

__device__ __forceinline__ float bsum256(float v, float* red) {
    int lane = threadIdx.x & 63, w = threadIdx.x >> 6;
#pragma unroll
    for (int off = 1; off < 64; off <<= 1) v += __shfl_xor(v, off);
    __syncthreads();
    if (lane == 0) red[w] = v;
    __syncthreads();
    return red[0] + red[1] + red[2] + red[3];
}

// ---------------------------------------------------------------------------
// prep_a: blocks 0-11 -> q0 = LN1(cls) @ Wq + bq; blocks 12-23 -> colga/colgb
// (ga/gb-weighted column sums of Wk). Block 0 zeroes the decide counters.
__global__ __launch_bounds__(256) void prep_a(
    const float* __restrict__ clsT, const float* __restrict__ ga,
    const float* __restrict__ gb, const float* __restrict__ Wq,
    const float* __restrict__ bq, const float* __restrict__ Wk,
    float* __restrict__ q0, float* __restrict__ colw, int* __restrict__ cnts)
{
    __shared__ float ys[768];
    __shared__ float red[4];
    __shared__ float4 partA[16][17];
    __shared__ float4 partB[16][17];
    int t = threadIdx.x;
    if (blockIdx.x == 0 && t < 16) cnts[t] = 0;
    if (blockIdx.x < 12) {
        float a0 = clsT[t], a1 = clsT[t + 256], a2 = clsT[t + 512];
        float mean = bsum256(a0 + a1 + a2, red) * (1.0f / 768.0f);
        float d0 = a0 - mean, d1 = a1 - mean, d2 = a2 - mean;
        float var = bsum256(d0 * d0 + d1 * d1 + d2 * d2, red) * (1.0f / 767.0f);
        float den = sqrtf(var) + 1e-6f;
        ys[t]       = (ga[t] * d0) / den + gb[t];
        ys[t + 256] = (ga[t + 256] * d1) / den + gb[t + 256];
        ys[t + 512] = (ga[t + 512] * d2) / den + gb[t + 512];
        __syncthreads();
        int c = blockIdx.x * 64 + (t & 15) * 4;
        int kq = t >> 4;
        float4 acc = {0.f, 0.f, 0.f, 0.f};
#pragma unroll 8
        for (int i = 0; i < 48; ++i) {
            int k = kq * 48 + i;
            float4 w = *(const float4*)&Wq[(size_t)k * 768 + c];
            float y = ys[k];
            acc.x = fmaf(y, w.x, acc.x); acc.y = fmaf(y, w.y, acc.y);
            acc.z = fmaf(y, w.z, acc.z); acc.w = fmaf(y, w.w, acc.w);
        }
        partA[kq][t & 15] = acc;
        __syncthreads();
        if (t < 16) {
            float4 s = {0.f, 0.f, 0.f, 0.f};
#pragma unroll
            for (int i = 0; i < 16; ++i) {
                float4 v = partA[i][t];
                s.x += v.x; s.y += v.y; s.z += v.z; s.w += v.w;
            }
            int cc = blockIdx.x * 64 + t * 4;
            float4 b4 = *(const float4*)&bq[cc];
            q0[cc] = s.x + b4.x; q0[cc + 1] = s.y + b4.y;
            q0[cc + 2] = s.z + b4.z; q0[cc + 3] = s.w + b4.w;
        }
    } else {
        int c = (blockIdx.x - 12) * 64 + (t & 15) * 4;
        int kq = t >> 4;
        float4 aa = {0.f, 0.f, 0.f, 0.f}, ab = {0.f, 0.f, 0.f, 0.f};
#pragma unroll 8
        for (int i = 0; i < 48; ++i) {
            int k = kq * 48 + i;
            float4 w = *(const float4*)&Wk[(size_t)k * 768 + c];
            float g = ga[k], h = gb[k];
            aa.x = fmaf(g, w.x, aa.x); aa.y = fmaf(g, w.y, aa.y);
            aa.z = fmaf(g, w.z, aa.z); aa.w = fmaf(g, w.w, aa.w);
            ab.x = fmaf(h, w.x, ab.x); ab.y = fmaf(h, w.y, ab.y);
            ab.z = fmaf(h, w.z, ab.z); ab.w = fmaf(h, w.w, ab.w);
        }
        partA[kq][t & 15] = aa;
        partB[kq][t & 15] = ab;
        __syncthreads();
        if (t < 16) {
            float4 sa = {0.f, 0.f, 0.f, 0.f}, sb = {0.f, 0.f, 0.f, 0.f};
#pragma unroll
            for (int i = 0; i < 16; ++i) {
                float4 va = partA[i][t], vb = partB[i][t];
                sa.x += va.x; sa.y += va.y; sa.z += va.z; sa.w += va.w;
                sb.x += vb.x; sb.y += vb.y; sb.z += vb.z; sb.w += vb.w;
            }
            int cc = (blockIdx.x - 12) * 64 + t * 4;
            *(float4*)&colw[cc] = sa;
            *(float4*)&colw[768 + cc] = sb;
        }
    }
}

// ---------------------------------------------------------------------------
// prep_b: wkq[k][h] = (Wk[k,h48..] . q0_h)/sqrt(48); block 0 also computes
// Sgw[h] (at 12304) and CgbC[h] (at 12320) from colga/colgb + bk.
__global__ __launch_bounds__(256) void prep_b(
    const float* __restrict__ Wk, const float* __restrict__ bk,
    const float* __restrict__ q0, const float* __restrict__ colw,
    float* __restrict__ wkqc)
{
    __shared__ float qs[768];
    int t = threadIdx.x;
    qs[t] = q0[t]; qs[t + 256] = q0[t + 256]; qs[t + 512] = q0[t + 512];
    __syncthreads();
    const float invs = 0.14433756729740643f;  // 1/sqrt(48)
    int kl = t >> 4, h = t & 15;
    int k = blockIdx.x * 16 + kl;
    const float* wr = Wk + (size_t)k * 768 + h * 48;
    const float* qh = qs + h * 48;
    float a = 0.f;
#pragma unroll
    for (int d = 0; d < 48; d += 4) {
        float4 w = *(const float4*)&wr[d];
        a += w.x * qh[d] + w.y * qh[d + 1] + w.z * qh[d + 2] + w.w * qh[d + 3];
    }
    wkqc[k * 16 + h] = a * invs;
    if (blockIdx.x == 0 && t < 16) {
        float cd = 0.f, sa = 0.f, sb = 0.f;
        for (int d = 0; d < 48; ++d) {
            int dd = t * 48 + d;
            cd = fmaf(bk[dd], qs[dd], cd);
            sa = fmaf(colw[dd], qs[dd], sa);
            sb = fmaf(colw[768 + dd], qs[dd], sb);
        }
        wkqc[12304 + t] = sa * invs;
        wkqc[12320 + t] = sb * invs + cd * invs;
    }
}

// ---------------------------------------------------------------------------
// SINGLE X pass: per 32-row chunk, compute each row's LN-expanded scores
// (register wk, raw moments), form w = exp(s)*rden, and immediately
// accumulate acc[h] += w*x while x is in registers. Emits up (wsum partials),
// upz (Σe), upc1 (Σ w*mean). grid 256 = (b 8) x (jc 32). 3 barriers/row.
__global__ __launch_bounds__(256) void score_upart(
    const float* __restrict__ tf, const float* __restrict__ clsT,
    const float* __restrict__ ga, const float* __restrict__ wkqc,
    float* __restrict__ up, float* __restrict__ upz, float* __restrict__ upc1)
{
    __shared__ float tr[256][17];
    __shared__ float partw[4][16];
    __shared__ float red[2][4][2];
    __shared__ float wrow[16];
    int t = threadIdx.x;
    int l = t & 63, w = t >> 6;

    float wk0[16], wk1[16], wk2[16];
    {
        const float4* p0 = (const float4*)(wkqc + t * 16);
        const float4* p1 = (const float4*)(wkqc + (t + 256) * 16);
        const float4* p2 = (const float4*)(wkqc + (t + 512) * 16);
#pragma unroll
        for (int q = 0; q < 4; ++q) {
            float4 v0 = p0[q], v1 = p1[q], v2 = p2[q];
            wk0[q * 4] = v0.x; wk0[q * 4 + 1] = v0.y; wk0[q * 4 + 2] = v0.z; wk0[q * 4 + 3] = v0.w;
            wk1[q * 4] = v1.x; wk1[q * 4 + 1] = v1.y; wk1[q * 4 + 2] = v1.z; wk1[q * 4 + 3] = v1.w;
            wk2[q * 4] = v2.x; wk2[q * 4 + 1] = v2.y; wk2[q * 4 + 2] = v2.z; wk2[q * 4 + 3] = v2.w;
        }
    }
    float ga0 = ga[t], ga1 = ga[t + 256], ga2 = ga[t + 512];
    float Sg = wkqc[12304 + (t & 15)];
    float Cg = wkqc[12320 + (t & 15)];

    float acc0[16], acc1[16], acc2[16];
#pragma unroll
    for (int h = 0; h < 16; ++h) { acc0[h] = 0.f; acc1[h] = 0.f; acc2[h] = 0.f; }
    float zacc = 0.f, c1acc = 0.f;

    int b = blockIdx.x & 7, jc = blockIdx.x >> 3;
    int j0 = jc * 32;
    const float* src0 = j0 ? (tf + ((size_t)b * 1023 + (j0 - 1)) * 768) : clsT;
    float x0 = src0[t], x1 = src0[t + 256], x2 = src0[t + 512];

    for (int r = 0; r < 32; ++r) {
        int j = j0 + r;
        float cx0 = x0, cx1 = x1, cx2 = x2;
        if (r < 31) {   // prefetch row j+1 (tf offset j, since tf holds j-1)
            const float* sp = tf + ((size_t)b * 1023 + j) * 768;
            x0 = sp[t]; x1 = sp[t + 256]; x2 = sp[t + 512];
        }
        float s1 = cx0 + cx1 + cx2;
        float s2 = fmaf(cx0, cx0, fmaf(cx1, cx1, cx2 * cx2));
        float g0 = ga0 * cx0, g1 = ga1 * cx1, g2 = ga2 * cx2;
        {
            float dt[16];
#pragma unroll
            for (int h = 0; h < 16; ++h)
                dt[h] = fmaf(g0, wk0[h], fmaf(g1, wk1[h], g2 * wk2[h]));
#pragma unroll
            for (int off = 1; off < 64; off <<= 1) {
                s1 += __shfl_xor(s1, off);
                s2 += __shfl_xor(s2, off);
            }
            if (l == 0) { red[r & 1][w][0] = s1; red[r & 1][w][1] = s2; }
#pragma unroll
            for (int h = 0; h < 16; ++h) tr[t][h] = dt[h];
        }
        __syncthreads();                       // B1
        {
            int hh = t & 15, ch = t >> 4;
            float v = 0.f;
#pragma unroll
            for (int i = 0; i < 16; ++i) v += tr[ch * 16 + i][hh];
            v += __shfl_xor(v, 16);
            v += __shfl_xor(v, 32);
            if (l < 16) partw[w][l] = v;
        }
        __syncthreads();                       // B2
        if (t < 16) {
            float dtot = partw[0][t] + partw[1][t] + partw[2][t] + partw[3][t];
            float s1t = red[r & 1][0][0] + red[r & 1][1][0] + red[r & 1][2][0] + red[r & 1][3][0];
            float s2t = red[r & 1][0][1] + red[r & 1][1][1] + red[r & 1][2][1] + red[r & 1][3][1];
            float mean = s1t * (1.0f / 768.0f);
            float var = (s2t - mean * s1t) * (1.0f / 767.0f);
            float rden = 1.0f / (sqrtf(var) + 1e-6f);
            float sv = rden * (dtot - mean * Sg) + Cg;
            float e = expf(sv);
            float wv = e * rden;
            wrow[t] = wv;
            zacc += e;                        // Σ e  (== Σ w/rden)
            c1acc = fmaf(wv, mean, c1acc);    // Σ w*mean
        }
        __syncthreads();                       // B3 (wrow visible)
#pragma unroll
        for (int h = 0; h < 16; ++h) {
            float wh = wrow[h];
            acc0[h] = fmaf(wh, cx0, acc0[h]);
            acc1[h] = fmaf(wh, cx1, acc1[h]);
            acc2[h] = fmaf(wh, cx2, acc2[h]);
        }
        // next row's B1 protects tr/partw/wrow reuse
    }

    float* o = up + (((size_t)b * 32 + jc) * 16) * 768;
#pragma unroll
    for (int h = 0; h < 16; ++h) {
        o[h * 768 + t] = acc0[h];
        o[h * 768 + t + 256] = acc1[h];
        o[h * 768 + t + 512] = acc2[h];
    }
    if (t < 16) {
        upz[((size_t)b * 32 + jc) * 16 + t] = zacc;
        upc1[((size_t)b * 32 + jc) * 16 + t] = c1acc;
    }
}

// ---------------------------------------------------------------------------
// o0 = (ga⊙(S−c1raw)/Z + gb) @ Wv_h + bv. grid (16 h, 8 b).
__global__ __launch_bounds__(256) void o0_k(
    const float* __restrict__ up, const float* __restrict__ upz,
    const float* __restrict__ upc1, const float* __restrict__ ga,
    const float* __restrict__ gb, const float* __restrict__ Wv,
    const float* __restrict__ bv, float* __restrict__ o0)
{
    __shared__ float us[768];
    __shared__ float part[4][64];
    int h = blockIdx.x, b = blockIdx.y, t = threadIdx.x;
    float s0 = 0.f, s1 = 0.f, s2 = 0.f;
#pragma unroll 8
    for (int jc = 0; jc < 32; ++jc) {
        const float* q = up + (((size_t)b * 32 + jc) * 16 + h) * 768;
        s0 += q[t]; s1 += q[t + 256]; s2 += q[t + 512];
    }
    float Z = 0.f, c1r = 0.f;
#pragma unroll 8
    for (int jc = 0; jc < 32; ++jc) {
        Z   += upz[((size_t)b * 32 + jc) * 16 + h];
        c1r += upc1[((size_t)b * 32 + jc) * 16 + h];
    }
    float rz = 1.0f / Z;
    us[t]       = ga[t] * ((s0 - c1r) * rz) + gb[t];
    us[t + 256] = ga[t + 256] * ((s1 - c1r) * rz) + gb[t + 256];
    us[t + 512] = ga[t + 512] * ((s2 - c1r) * rz) + gb[t + 512];
    __syncthreads();
    int dd = t & 63, kg = t >> 6;
    float a = 0.f;
    if (dd < 48) {
#pragma unroll 8
        for (int i = 0; i < 192; ++i) {
            int k = kg * 192 + i;
            a = fmaf(us[k], Wv[(size_t)k * 768 + h * 48 + dd], a);
        }
    }
    part[kg][dd] = a;
    __syncthreads();
    if (t < 48)
        o0[(size_t)b * 768 + h * 48 + t] =
            part[0][t] + part[1][t] + part[2][t] + part[3][t] + bv[h * 48 + t];
}

// ---------------------------------------------------------------------------
// x2 = clsT + o0 @ Wo + bo. grid (12, 8).
__global__ __launch_bounds__(256) void x2_k(
    const float* __restrict__ o0, const float* __restrict__ Wo,
    const float* __restrict__ bo, const float* __restrict__ clsT,
    float* __restrict__ x2w)
{
    __shared__ float ys[768];
    __shared__ float4 part[16][17];
    int b = blockIdx.y, t = threadIdx.x;
    const float* xr = o0 + (size_t)b * 768;
    ys[t] = xr[t]; ys[t + 256] = xr[t + 256]; ys[t + 512] = xr[t + 512];
    __syncthreads();
    int c = blockIdx.x * 64 + (t & 15) * 4;
    int kq = t >> 4;
    float4 acc = {0.f, 0.f, 0.f, 0.f};
#pragma unroll 8
    for (int i = 0; i < 48; ++i) {
        int k = kq * 48 + i;
        float4 w = *(const float4*)&Wo[(size_t)k * 768 + c];
        float y = ys[k];
        acc.x = fmaf(y, w.x, acc.x); acc.y = fmaf(y, w.y, acc.y);
        acc.z = fmaf(y, w.z, acc.z); acc.w = fmaf(y, w.w, acc.w);
    }
    part[kq][t & 15] = acc;
    __syncthreads();
    if (t < 16) {
        float4 s = {0.f, 0.f, 0.f, 0.f};
#pragma unroll
        for (int i = 0; i < 16; ++i) {
            float4 v = part[i][t];
            s.x += v.x; s.y += v.y; s.z += v.z; s.w += v.w;
        }
        int cc = blockIdx.x * 64 + t * 4;
        float4 b4 = *(const float4*)&bo[cc];
        float4 r4 = *(const float4*)&clsT[cc];
        float* o = x2w + (size_t)b * 768 + cc;
        o[0] = s.x + b4.x + r4.x; o[1] = s.y + b4.y + r4.y;
        o[2] = s.z + b4.z + r4.z; o[3] = s.w + b4.w + r4.w;
    }
}

// ---------------------------------------------------------------------------
// f1 = relu(LN2(x2) @ W1 + b1), LN fused. grid (24, 8).
__global__ __launch_bounds__(256) void f1_k(
    const float* __restrict__ x2w, const float* __restrict__ ga,
    const float* __restrict__ gb, const float* __restrict__ W1,
    const float* __restrict__ b1, float* __restrict__ f1w)
{
    __shared__ float ys[768];
    __shared__ float red[4];
    __shared__ float4 part[8][33];
    int b = blockIdx.y, t = threadIdx.x;
    const float* xr = x2w + (size_t)b * 768;
    float a0 = xr[t], a1 = xr[t + 256], a2 = xr[t + 512];
    float mean = bsum256(a0 + a1 + a2, red) * (1.0f / 768.0f);
    float d0 = a0 - mean, d1 = a1 - mean, d2 = a2 - mean;
    float var = bsum256(d0 * d0 + d1 * d1 + d2 * d2, red) * (1.0f / 767.0f);
    float den = sqrtf(var) + 1e-6f;
    ys[t]       = (ga[t] * d0) / den + gb[t];
    ys[t + 256] = (ga[t + 256] * d1) / den + gb[t + 256];
    ys[t + 512] = (ga[t + 512] * d2) / den + gb[t + 512];
    __syncthreads();
    int c = blockIdx.x * 128 + (t & 31) * 4;
    int kq = t >> 5;
    float4 acc = {0.f, 0.f, 0.f, 0.f};
#pragma unroll 8
    for (int i = 0; i < 96; ++i) {
        int k = kq * 96 + i;
        float4 w = *(const float4*)&W1[(size_t)k * 3072 + c];
        float y = ys[k];
        acc.x = fmaf(y, w.x, acc.x); acc.y = fmaf(y, w.y, acc.y);
        acc.z = fmaf(y, w.z, acc.z); acc.w = fmaf(y, w.w, acc.w);
    }
    part[kq][t & 31] = acc;
    __syncthreads();
    if (t < 32) {
        float4 s = {0.f, 0.f, 0.f, 0.f};
#pragma unroll
        for (int i = 0; i < 8; ++i) {
            float4 v = part[i][t];
            s.x += v.x; s.y += v.y; s.z += v.z; s.w += v.w;
        }
        int cc = blockIdx.x * 128 + t * 4;
        float4 b4 = *(const float4*)&b1[cc];
        float* o = f1w + (size_t)b * 3072 + cc;
        o[0] = fmaxf(s.x + b4.x, 0.f); o[1] = fmaxf(s.y + b4.y, 0.f);
        o[2] = fmaxf(s.z + b4.z, 0.f); o[3] = fmaxf(s.w + b4.w, 0.f);
    }
}

// ---------------------------------------------------------------------------
// x3 = x2 + f1 @ W2 + b2. grid (12, 8). Tail-free.
__global__ __launch_bounds__(256) void x3_k(
    const float* __restrict__ f1w, const float* __restrict__ W2,
    const float* __restrict__ b2, const float* __restrict__ x2w,
    float* __restrict__ x3w)
{
    __shared__ float ys[3072];
    __shared__ float4 part[16][17];
    int b = blockIdx.y, t = threadIdx.x;
    const float* xr = f1w + (size_t)b * 3072;
    for (int i = t; i < 3072; i += 256) ys[i] = xr[i];
    __syncthreads();
    int c = blockIdx.x * 64 + (t & 15) * 4;
    int kq = t >> 4;
    float4 acc = {0.f, 0.f, 0.f, 0.f};
#pragma unroll 8
    for (int i = 0; i < 192; ++i) {
        int k = kq * 192 + i;
        float4 w = *(const float4*)&W2[(size_t)k * 768 + c];
        float y = ys[k];
        acc.x = fmaf(y, w.x, acc.x); acc.y = fmaf(y, w.y, acc.y);
        acc.z = fmaf(y, w.z, acc.z); acc.w = fmaf(y, w.w, acc.w);
    }
    part[kq][t & 15] = acc;
    __syncthreads();
    if (t < 16) {
        float4 s = {0.f, 0.f, 0.f, 0.f};
#pragma unroll
        for (int i = 0; i < 16; ++i) {
            float4 v = part[i][t];
            s.x += v.x; s.y += v.y; s.z += v.z; s.w += v.w;
        }
        int cc = blockIdx.x * 64 + t * 4;
        float4 b4 = *(const float4*)&b2[cc];
        const float* x2r = x2w + (size_t)b * 768 + cc;
        float* o = x3w + (size_t)b * 768 + cc;
        o[0] = x2r[0] + s.x + b4.x; o[1] = x2r[1] + s.y + b4.y;
        o[2] = x2r[2] + s.z + b4.z; o[3] = x2r[3] + s.w + b4.w;
    }
}

// ---------------------------------------------------------------------------
// Head logits, k-split (grid 8 kg x 8 b), LNf fused, double partials.
// LAST block per batch (atomic counter, no spinning) sums the 8 partials,
// writes class logits + entropy -> kk, and ranks the POOL LOGITS directly
// (top_k(softmax(z)) == top_k(z): exp monotonic, uniform Z).
__global__ __launch_bounds__(256) void logits_part(
    const float* __restrict__ x3w, const float* __restrict__ ga,
    const float* __restrict__ gb, const float* __restrict__ Wpool,
    const float* __restrict__ Wcls, double* __restrict__ lp,
    const float* __restrict__ bpool, const float* __restrict__ bcls,
    float* __restrict__ out, int* __restrict__ topw, int* __restrict__ kkw,
    int* __restrict__ cnts)
{
    __shared__ float ys[768];
    __shared__ float red[4];
    __shared__ double sPd[100];
    __shared__ double sC7d[7];
    __shared__ int sOld;
    int kg = blockIdx.x, b = blockIdx.y, t = threadIdx.x;
    const float* xr = x3w + (size_t)b * 768;
    float a0 = xr[t], a1 = xr[t + 256], a2 = xr[t + 512];
    float mean = bsum256(a0 + a1 + a2, red) * (1.0f / 768.0f);
    float d0 = a0 - mean, d1 = a1 - mean, d2 = a2 - mean;
    float var = bsum256(d0 * d0 + d1 * d1 + d2 * d2, red) * (1.0f / 767.0f);
    float den = sqrtf(var) + 1e-6f;
    ys[t]       = (ga[t] * d0) / den + gb[t];
    ys[t + 256] = (ga[t + 256] * d1) / den + gb[t + 256];
    ys[t + 512] = (ga[t + 512] * d2) / den + gb[t + 512];
    __syncthreads();
    int kbase = kg * 96;
    if (t < 100) {
        double a = 0.0;
#pragma unroll 8
        for (int i = 0; i < 96; ++i) {
            int k = kbase + i;
            a = fma((double)ys[k], (double)Wpool[k * 100 + t], a);
        }
        lp[((size_t)b * 8 + kg) * 112 + t] = a;
    } else if (t < 107) {
        int c = t - 100;
        double a = 0.0;
#pragma unroll 8
        for (int i = 0; i < 96; ++i) {
            int k = kbase + i;
            a = fma((double)ys[k], (double)Wcls[k * 7 + c], a);
        }
        lp[((size_t)b * 8 + kg) * 112 + t] = a;
    }

    // ---- last-block decide (one atomic per block; non-last blocks exit) ----
    __syncthreads();     // drain this block's lp stores
    __threadfence();
    if (t == 0)
        sOld = __hip_atomic_fetch_add(&cnts[b], 1, __ATOMIC_ACQ_REL,
                                      __HIP_MEMORY_SCOPE_AGENT);
    __syncthreads();
    if (sOld != 7) return;

    if (t < 107) {
        double a = (t < 100) ? (double)bpool[t] : (double)bcls[t - 100];
#pragma unroll
        for (int g = 0; g < 8; ++g) a += lp[((size_t)b * 8 + g) * 112 + t];
        if (t < 100) sPd[t] = a;
        else {
            sC7d[t - 100] = a;
            out[OUT_CLS_OFF + b * 7 + (t - 100)] = (float)a;
        }
    }
    __syncthreads();
    if (t == 0) {
        double m7 = sC7d[0];
        for (int j = 1; j < 7; ++j) m7 = fmax(m7, sC7d[j]);
        double es[7]; double z = 0.0;
        for (int j = 0; j < 7; ++j) { es[j] = exp(sC7d[j] - m7); z += es[j]; }
        double ent = 0.0;
        for (int j = 0; j < 7; ++j) { double pr = es[j] / z; ent -= pr * log(pr + 1e-9); }
        double ne = ent / log(7.0);
        int kk = (int)floor(1.0 + ne * 99.0);
        kkw[b] = kk < 1 ? 1 : (kk > 100 ? 100 : kk);
    }
    if (t < 100) {
        double pi = sPd[t];     // rank on logits: same order as probabilities
        int r = 0;
#pragma unroll 4
        for (int j = 0; j < 100; ++j) {
            double pj = sPd[j];
            r += (pj > pi) || (pj == pi && j < t);
        }
        topw[b * 100 + r] = t;  // descending, stable (lower index first)
    }
}

// ---------------------------------------------------------------------------
// gather: out[b, r, :] = (r < kk[b]) ? pool[top[b][r], :] : 0. grid (100, 8).
__global__ __launch_bounds__(192) void gather_k(
    const float* __restrict__ pool, const int* __restrict__ topw,
    const int* __restrict__ kkw, float* __restrict__ out)
{
    int r = blockIdx.x, b = blockIdx.y, t = threadIdx.x;
    int idx = topw[b * 100 + r];
    bool keep = r < kkw[b];
    const float4* src = (const float4*)(pool + (size_t)idx * 768);
    float4* dst = (float4*)(out + (size_t)b * 76800 + (size_t)r * 768);
    float4 z = {0.f, 0.f, 0.f, 0.f};
    dst[t] = keep ? src[t] : z;
}

// ---------------------------------------------------------------------------
extern "C" void kernel_launch(void* const* d_in, const int* in_sizes, int n_in,
                              void* d_out, int out_size, void* d_ws, size_t ws_size,
                              hipStream_t stream) {
    (void)in_sizes; (void)n_in; (void)out_size; (void)ws_size;
    const float* tf    = (const float*)d_in[0];
    const float* pool  = (const float*)d_in[1];
    const float* clsT  = (const float*)d_in[2];
    const float* Wq    = (const float*)d_in[3];
    const float* bq    = (const float*)d_in[4];
    const float* Wk    = (const float*)d_in[5];
    const float* bk    = (const float*)d_in[6];
    const float* Wv    = (const float*)d_in[7];
    const float* bv    = (const float*)d_in[8];
    const float* Wo    = (const float*)d_in[9];
    const float* bo    = (const float*)d_in[10];
    const float* ln1a  = (const float*)d_in[11];
    const float* ln1b  = (const float*)d_in[12];
    const float* ln2a  = (const float*)d_in[13];
    const float* ln2b  = (const float*)d_in[14];
    const float* W1    = (const float*)d_in[15];
    const float* b1    = (const float*)d_in[16];
    const float* W2    = (const float*)d_in[17];
    const float* b2    = (const float*)d_in[18];
    const float* lnfa  = (const float*)d_in[19];
    const float* lnfb  = (const float*)d_in[20];
    const float* Wpool = (const float*)d_in[21];
    const float* bpool = (const float*)d_in[22];
    const float* Wcls  = (const float*)d_in[23];
    const float* bcls  = (const float*)d_in[24];
    float* out = (float*)d_out;
    char* ws = (char*)d_ws;

    float*  wkqc  = (float*)(ws + 0);           // 49,408
    float*  q0    = (float*)(ws + 49408);       // 3,072
    float*  colw  = (float*)(ws + 52480);       // 6,144
    float*  up    = (float*)(ws + 58624);       // 12,582,912
    float*  upz   = (float*)(ws + 12641536);    // 16,384
    float*  upc1  = (float*)(ws + 12657920);    // 16,384
    float*  o0    = (float*)(ws + 12674304);    // 24,576
    float*  x2w   = (float*)(ws + 12698880);    // 24,576
    float*  f1w   = (float*)(ws + 12723456);    // 98,304
    float*  x3w   = (float*)(ws + 12821760);    // 24,576
    int*    topw  = (int*)(ws + 12846336);      // 3,200
    int*    kkw   = (int*)(ws + 12849536);      // 32
    double* lp    = (double*)(ws + 12849568);   // 57,344 (8-aligned)
    int*    cnts  = (int*)(ws + 12906912);      // 64   (total ~12.9 MB)

    prep_a<<<24, 256, 0, stream>>>(clsT, ln1a, ln1b, Wq, bq, Wk, q0, colw, cnts);
    prep_b<<<48, 256, 0, stream>>>(Wk, bk, q0, colw, wkqc);
    score_upart<<<256, 256, 0, stream>>>(tf, clsT, ln1a, wkqc, up, upz, upc1);
    o0_k<<<dim3(16, 8), 256, 0, stream>>>(up, upz, upc1, ln1a, ln1b, Wv, bv, o0);
    x2_k<<<dim3(12, 8), 256, 0, stream>>>(o0, Wo, bo, clsT, x2w);
    f1_k<<<dim3(24, 8), 256, 0, stream>>>(x2w, ln2a, ln2b, W1, b1, f1w);
    x3_k<<<dim3(12, 8), 256, 0, stream>>>(f1w, W2, b2, x2w, x3w);
    logits_part<<<dim3(8, 8), 256, 0, stream>>>(x3w, lnfa, lnfb, Wpool, Wcls,
                                                lp, bpool, bcls, out, topw,
                                                kkw, cnts);
    gather_k<<<dim3(100, 8), 192, 0, stream>>>(pool, topw, kkw, out);
}

// Round 15
// 107.719 us; speedup vs baseline: 1.0735x; 1.0735x over previous
//
#include <hip/hip_runtime.h>

// ---------------------------------------------------------------------------
// PromptSelector — collapsed algebra, 9 launches.
//   scores[b,h,j] = rden_j*(dot(ga*x_j, wk[:,h]) - mean_j*Sgw[h]) + CgbC[h]
//   w_j = exp(s_j)*rden_j  (unnormalized; division deferred to o0_k:
//        u = ga*(Σ w x − c1raw)/Z + gb, Z = Σ e, c1raw = Σ w*mean)
// Round 15: R14's merged score_upart spilled (compiler clamped VGPR 150->76,
// R8 lesson) and ran 1 block/CU with 3 barriers/row. Fixes: (1)
// __launch_bounds__(256,2) permits 256 VGPR at 2 blocks/CU; (2) grid 512
// (16 rows/chunk) -> 8 waves/CU; (3) software-pipelined accumulate (row r-1
// accumulated during row r's barrier window) -> 2 barriers/row.
// ---------------------------------------------------------------------------

#define OUT_CLS_OFF 614400   // 8*100*768

__device__ __forceinline__ float bsum256(float v, float* red) {
    int lane = threadIdx.x & 63, w = threadIdx.x >> 6;
#pragma unroll
    for (int off = 1; off < 64; off <<= 1) v += __shfl_xor(v, off);
    __syncthreads();
    if (lane == 0) red[w] = v;
    __syncthreads();
    return red[0] + red[1] + red[2] + red[3];
}

// ---------------------------------------------------------------------------
// prep_a: blocks 0-11 -> q0 = LN1(cls) @ Wq + bq; blocks 12-23 -> colga/colgb
// (ga/gb-weighted column sums of Wk). Block 0 zeroes the decide counters.
__global__ __launch_bounds__(256) void prep_a(
    const float* __restrict__ clsT, const float* __restrict__ ga,
    const float* __restrict__ gb, const float* __restrict__ Wq,
    const float* __restrict__ bq, const float* __restrict__ Wk,
    float* __restrict__ q0, float* __restrict__ colw, int* __restrict__ cnts)
{
    __shared__ float ys[768];
    __shared__ float red[4];
    __shared__ float4 partA[16][17];
    __shared__ float4 partB[16][17];
    int t = threadIdx.x;
    if (blockIdx.x == 0 && t < 16) cnts[t] = 0;
    if (blockIdx.x < 12) {
        float a0 = clsT[t], a1 = clsT[t + 256], a2 = clsT[t + 512];
        float mean = bsum256(a0 + a1 + a2, red) * (1.0f / 768.0f);
        float d0 = a0 - mean, d1 = a1 - mean, d2 = a2 - mean;
        float var = bsum256(d0 * d0 + d1 * d1 + d2 * d2, red) * (1.0f / 767.0f);
        float den = sqrtf(var) + 1e-6f;
        ys[t]       = (ga[t] * d0) / den + gb[t];
        ys[t + 256] = (ga[t + 256] * d1) / den + gb[t + 256];
        ys[t + 512] = (ga[t + 512] * d2) / den + gb[t + 512];
        __syncthreads();
        int c = blockIdx.x * 64 + (t & 15) * 4;
        int kq = t >> 4;
        float4 acc = {0.f, 0.f, 0.f, 0.f};
#pragma unroll 8
        for (int i = 0; i < 48; ++i) {
            int k = kq * 48 + i;
            float4 w = *(const float4*)&Wq[(size_t)k * 768 + c];
            float y = ys[k];
            acc.x = fmaf(y, w.x, acc.x); acc.y = fmaf(y, w.y, acc.y);
            acc.z = fmaf(y, w.z, acc.z); acc.w = fmaf(y, w.w, acc.w);
        }
        partA[kq][t & 15] = acc;
        __syncthreads();
        if (t < 16) {
            float4 s = {0.f, 0.f, 0.f, 0.f};
#pragma unroll
            for (int i = 0; i < 16; ++i) {
                float4 v = partA[i][t];
                s.x += v.x; s.y += v.y; s.z += v.z; s.w += v.w;
            }
            int cc = blockIdx.x * 64 + t * 4;
            float4 b4 = *(const float4*)&bq[cc];
            q0[cc] = s.x + b4.x; q0[cc + 1] = s.y + b4.y;
            q0[cc + 2] = s.z + b4.z; q0[cc + 3] = s.w + b4.w;
        }
    } else {
        int c = (blockIdx.x - 12) * 64 + (t & 15) * 4;
        int kq = t >> 4;
        float4 aa = {0.f, 0.f, 0.f, 0.f}, ab = {0.f, 0.f, 0.f, 0.f};
#pragma unroll 8
        for (int i = 0; i < 48; ++i) {
            int k = kq * 48 + i;
            float4 w = *(const float4*)&Wk[(size_t)k * 768 + c];
            float g = ga[k], h = gb[k];
            aa.x = fmaf(g, w.x, aa.x); aa.y = fmaf(g, w.y, aa.y);
            aa.z = fmaf(g, w.z, aa.z); aa.w = fmaf(g, w.w, aa.w);
            ab.x = fmaf(h, w.x, ab.x); ab.y = fmaf(h, w.y, ab.y);
            ab.z = fmaf(h, w.z, ab.z); ab.w = fmaf(h, w.w, ab.w);
        }
        partA[kq][t & 15] = aa;
        partB[kq][t & 15] = ab;
        __syncthreads();
        if (t < 16) {
            float4 sa = {0.f, 0.f, 0.f, 0.f}, sb = {0.f, 0.f, 0.f, 0.f};
#pragma unroll
            for (int i = 0; i < 16; ++i) {
                float4 va = partA[i][t], vb = partB[i][t];
                sa.x += va.x; sa.y += va.y; sa.z += va.z; sa.w += va.w;
                sb.x += vb.x; sb.y += vb.y; sb.z += vb.z; sb.w += vb.w;
            }
            int cc = (blockIdx.x - 12) * 64 + t * 4;
            *(float4*)&colw[cc] = sa;
            *(float4*)&colw[768 + cc] = sb;
        }
    }
}

// ---------------------------------------------------------------------------
// prep_b: wkq[k][h] = (Wk[k,h48..] . q0_h)/sqrt(48); block 0 also computes
// Sgw[h] (at 12304) and CgbC[h] (at 12320) from colga/colgb + bk.
__global__ __launch_bounds__(256) void prep_b(
    const float* __restrict__ Wk, const float* __restrict__ bk,
    const float* __restrict__ q0, const float* __restrict__ colw,
    float* __restrict__ wkqc)
{
    __shared__ float qs[768];
    int t = threadIdx.x;
    qs[t] = q0[t]; qs[t + 256] = q0[t + 256]; qs[t + 512] = q0[t + 512];
    __syncthreads();
    const float invs = 0.14433756729740643f;  // 1/sqrt(48)
    int kl = t >> 4, h = t & 15;
    int k = blockIdx.x * 16 + kl;
    const float* wr = Wk + (size_t)k * 768 + h * 48;
    const float* qh = qs + h * 48;
    float a = 0.f;
#pragma unroll
    for (int d = 0; d < 48; d += 4) {
        float4 w = *(const float4*)&wr[d];
        a += w.x * qh[d] + w.y * qh[d + 1] + w.z * qh[d + 2] + w.w * qh[d + 3];
    }
    wkqc[k * 16 + h] = a * invs;
    if (blockIdx.x == 0 && t < 16) {
        float cd = 0.f, sa = 0.f, sb = 0.f;
        for (int d = 0; d < 48; ++d) {
            int dd = t * 48 + d;
            cd = fmaf(bk[dd], qs[dd], cd);
            sa = fmaf(colw[dd], qs[dd], sa);
            sb = fmaf(colw[768 + dd], qs[dd], sb);
        }
        wkqc[12304 + t] = sa * invs;
        wkqc[12320 + t] = sb * invs + cd * invs;
    }
}

// ---------------------------------------------------------------------------
// SINGLE X pass: 16-row chunks, grid 512 = (b 8) x (jc 64), 2 blocks/CU.
// Per row: score (2 barriers), pipelined accumulate of the PREVIOUS row
// between B1/B2 (wrow double-buffered). __launch_bounds__(256,2) allows
// 256 VGPR so wk[48]+acc[48] stay in registers (R14 spilled at default).
__global__ __launch_bounds__(256, 2) void score_upart(
    const float* __restrict__ tf, const float* __restrict__ clsT,
    const float* __restrict__ ga, const float* __restrict__ wkqc,
    float* __restrict__ up, float* __restrict__ upz, float* __restrict__ upc1)
{
    __shared__ float tr[256][17];
    __shared__ float partw[4][16];
    __shared__ float red[2][4][2];
    __shared__ float wrow[2][16];
    int t = threadIdx.x;
    int l = t & 63, w = t >> 6;

    float wk0[16], wk1[16], wk2[16];
    {
        const float4* p0 = (const float4*)(wkqc + t * 16);
        const float4* p1 = (const float4*)(wkqc + (t + 256) * 16);
        const float4* p2 = (const float4*)(wkqc + (t + 512) * 16);
#pragma unroll
        for (int q = 0; q < 4; ++q) {
            float4 v0 = p0[q], v1 = p1[q], v2 = p2[q];
            wk0[q * 4] = v0.x; wk0[q * 4 + 1] = v0.y; wk0[q * 4 + 2] = v0.z; wk0[q * 4 + 3] = v0.w;
            wk1[q * 4] = v1.x; wk1[q * 4 + 1] = v1.y; wk1[q * 4 + 2] = v1.z; wk1[q * 4 + 3] = v1.w;
            wk2[q * 4] = v2.x; wk2[q * 4 + 1] = v2.y; wk2[q * 4 + 2] = v2.z; wk2[q * 4 + 3] = v2.w;
        }
    }
    float ga0 = ga[t], ga1 = ga[t + 256], ga2 = ga[t + 512];
    float Sg = wkqc[12304 + (t & 15)];
    float Cg = wkqc[12320 + (t & 15)];

    float acc0[16], acc1[16], acc2[16];
#pragma unroll
    for (int h = 0; h < 16; ++h) { acc0[h] = 0.f; acc1[h] = 0.f; acc2[h] = 0.f; }
    float zacc = 0.f, c1acc = 0.f;

    int b = blockIdx.x & 7, jc = blockIdx.x >> 3;   // jc 0..63
    int j0 = jc * 16;
    const float* src0 = j0 ? (tf + ((size_t)b * 1023 + (j0 - 1)) * 768) : clsT;
    float xc0 = src0[t], xc1 = src0[t + 256], xc2 = src0[t + 512];
    float xp0 = 0.f, xp1 = 0.f, xp2 = 0.f;   // previous row (pending acc)

    for (int r = 0; r < 16; ++r) {
        int j = j0 + r;
        float s1 = xc0 + xc1 + xc2;
        float s2 = fmaf(xc0, xc0, fmaf(xc1, xc1, xc2 * xc2));
        float g0 = ga0 * xc0, g1 = ga1 * xc1, g2 = ga2 * xc2;
        float xn0 = 0.f, xn1 = 0.f, xn2 = 0.f;
        if (r < 15) {   // prefetch row j+1 (tf offset j, since tf holds j-1)
            const float* sp = tf + ((size_t)b * 1023 + j) * 768;
            xn0 = sp[t]; xn1 = sp[t + 256]; xn2 = sp[t + 512];
        }
        {
            float dt[16];
#pragma unroll
            for (int h = 0; h < 16; ++h)
                dt[h] = fmaf(g0, wk0[h], fmaf(g1, wk1[h], g2 * wk2[h]));
#pragma unroll
            for (int off = 1; off < 64; off <<= 1) {
                s1 += __shfl_xor(s1, off);
                s2 += __shfl_xor(s2, off);
            }
            if (l == 0) { red[r & 1][w][0] = s1; red[r & 1][w][1] = s2; }
#pragma unroll
            for (int h = 0; h < 16; ++h) tr[t][h] = dt[h];
        }
        __syncthreads();                       // B1 (also publishes wrow[r-1])
        // pipelined accumulate of row r-1 (wrow[(r-1)&1] safe after B1)
        if (r > 0) {
#pragma unroll
            for (int h = 0; h < 16; ++h) {
                float wh = wrow[(r - 1) & 1][h];
                acc0[h] = fmaf(wh, xp0, acc0[h]);
                acc1[h] = fmaf(wh, xp1, acc1[h]);
                acc2[h] = fmaf(wh, xp2, acc2[h]);
            }
        }
        {
            int hh = t & 15, ch = t >> 4;
            float v = 0.f;
#pragma unroll
            for (int i = 0; i < 16; ++i) v += tr[ch * 16 + i][hh];
            v += __shfl_xor(v, 16);
            v += __shfl_xor(v, 32);
            if (l < 16) partw[w][l] = v;
        }
        __syncthreads();                       // B2
        if (t < 16) {
            float dtot = partw[0][t] + partw[1][t] + partw[2][t] + partw[3][t];
            float s1t = red[r & 1][0][0] + red[r & 1][1][0] + red[r & 1][2][0] + red[r & 1][3][0];
            float s2t = red[r & 1][0][1] + red[r & 1][1][1] + red[r & 1][2][1] + red[r & 1][3][1];
            float mean = s1t * (1.0f / 768.0f);
            float var = (s2t - mean * s1t) * (1.0f / 767.0f);
            float rden = 1.0f / (sqrtf(var) + 1e-6f);
            float sv = rden * (dtot - mean * Sg) + Cg;
            float e = expf(sv);
            float wv = e * rden;
            wrow[r & 1][t] = wv;
            zacc += e;                        // Σ e  (== Σ w/rden)
            c1acc = fmaf(wv, mean, c1acc);    // Σ w*mean
        }
        xp0 = xc0; xp1 = xc1; xp2 = xc2;
        xc0 = xn0; xc1 = xn1; xc2 = xn2;
        // next row's B1 publishes wrow[r&1] and protects tr/partw reuse
    }
    __syncthreads();                           // publish wrow[15&1]
#pragma unroll
    for (int h = 0; h < 16; ++h) {             // final row's accumulate
        float wh = wrow[15 & 1][h];
        acc0[h] = fmaf(wh, xp0, acc0[h]);
        acc1[h] = fmaf(wh, xp1, acc1[h]);
        acc2[h] = fmaf(wh, xp2, acc2[h]);
    }

    float* o = up + (((size_t)b * 64 + jc) * 16) * 768;
#pragma unroll
    for (int h = 0; h < 16; ++h) {
        o[h * 768 + t] = acc0[h];
        o[h * 768 + t + 256] = acc1[h];
        o[h * 768 + t + 512] = acc2[h];
    }
    if (t < 16) {
        upz[((size_t)b * 64 + jc) * 16 + t] = zacc;
        upc1[((size_t)b * 64 + jc) * 16 + t] = c1acc;
    }
}

// ---------------------------------------------------------------------------
// o0 = (ga⊙(S−c1raw)/Z + gb) @ Wv_h + bv. grid (16 h, 8 b). 64 partials.
__global__ __launch_bounds__(256) void o0_k(
    const float* __restrict__ up, const float* __restrict__ upz,
    const float* __restrict__ upc1, const float* __restrict__ ga,
    const float* __restrict__ gb, const float* __restrict__ Wv,
    const float* __restrict__ bv, float* __restrict__ o0)
{
    __shared__ float us[768];
    __shared__ float part[4][64];
    int h = blockIdx.x, b = blockIdx.y, t = threadIdx.x;
    float s0 = 0.f, s1 = 0.f, s2 = 0.f;
#pragma unroll 8
    for (int jc = 0; jc < 64; ++jc) {
        const float* q = up + (((size_t)b * 64 + jc) * 16 + h) * 768;
        s0 += q[t]; s1 += q[t + 256]; s2 += q[t + 512];
    }
    float Z = 0.f, c1r = 0.f;
#pragma unroll 8
    for (int jc = 0; jc < 64; ++jc) {
        Z   += upz[((size_t)b * 64 + jc) * 16 + h];
        c1r += upc1[((size_t)b * 64 + jc) * 16 + h];
    }
    float rz = 1.0f / Z;
    us[t]       = ga[t] * ((s0 - c1r) * rz) + gb[t];
    us[t + 256] = ga[t + 256] * ((s1 - c1r) * rz) + gb[t + 256];
    us[t + 512] = ga[t + 512] * ((s2 - c1r) * rz) + gb[t + 512];
    __syncthreads();
    int dd = t & 63, kg = t >> 6;
    float a = 0.f;
    if (dd < 48) {
#pragma unroll 8
        for (int i = 0; i < 192; ++i) {
            int k = kg * 192 + i;
            a = fmaf(us[k], Wv[(size_t)k * 768 + h * 48 + dd], a);
        }
    }
    part[kg][dd] = a;
    __syncthreads();
    if (t < 48)
        o0[(size_t)b * 768 + h * 48 + t] =
            part[0][t] + part[1][t] + part[2][t] + part[3][t] + bv[h * 48 + t];
}

// ---------------------------------------------------------------------------
// x2 = clsT + o0 @ Wo + bo. grid (12, 8).
__global__ __launch_bounds__(256) void x2_k(
    const float* __restrict__ o0, const float* __restrict__ Wo,
    const float* __restrict__ bo, const float* __restrict__ clsT,
    float* __restrict__ x2w)
{
    __shared__ float ys[768];
    __shared__ float4 part[16][17];
    int b = blockIdx.y, t = threadIdx.x;
    const float* xr = o0 + (size_t)b * 768;
    ys[t] = xr[t]; ys[t + 256] = xr[t + 256]; ys[t + 512] = xr[t + 512];
    __syncthreads();
    int c = blockIdx.x * 64 + (t & 15) * 4;
    int kq = t >> 4;
    float4 acc = {0.f, 0.f, 0.f, 0.f};
#pragma unroll 8
    for (int i = 0; i < 48; ++i) {
        int k = kq * 48 + i;
        float4 w = *(const float4*)&Wo[(size_t)k * 768 + c];
        float y = ys[k];
        acc.x = fmaf(y, w.x, acc.x); acc.y = fmaf(y, w.y, acc.y);
        acc.z = fmaf(y, w.z, acc.z); acc.w = fmaf(y, w.w, acc.w);
    }
    part[kq][t & 15] = acc;
    __syncthreads();
    if (t < 16) {
        float4 s = {0.f, 0.f, 0.f, 0.f};
#pragma unroll
        for (int i = 0; i < 16; ++i) {
            float4 v = part[i][t];
            s.x += v.x; s.y += v.y; s.z += v.z; s.w += v.w;
        }
        int cc = blockIdx.x * 64 + t * 4;
        float4 b4 = *(const float4*)&bo[cc];
        float4 r4 = *(const float4*)&clsT[cc];
        float* o = x2w + (size_t)b * 768 + cc;
        o[0] = s.x + b4.x + r4.x; o[1] = s.y + b4.y + r4.y;
        o[2] = s.z + b4.z + r4.z; o[3] = s.w + b4.w + r4.w;
    }
}

// ---------------------------------------------------------------------------
// f1 = relu(LN2(x2) @ W1 + b1), LN fused. grid (24, 8).
__global__ __launch_bounds__(256) void f1_k(
    const float* __restrict__ x2w, const float* __restrict__ ga,
    const float* __restrict__ gb, const float* __restrict__ W1,
    const float* __restrict__ b1, float* __restrict__ f1w)
{
    __shared__ float ys[768];
    __shared__ float red[4];
    __shared__ float4 part[8][33];
    int b = blockIdx.y, t = threadIdx.x;
    const float* xr = x2w + (size_t)b * 768;
    float a0 = xr[t], a1 = xr[t + 256], a2 = xr[t + 512];
    float mean = bsum256(a0 + a1 + a2, red) * (1.0f / 768.0f);
    float d0 = a0 - mean, d1 = a1 - mean, d2 = a2 - mean;
    float var = bsum256(d0 * d0 + d1 * d1 + d2 * d2, red) * (1.0f / 767.0f);
    float den = sqrtf(var) + 1e-6f;
    ys[t]       = (ga[t] * d0) / den + gb[t];
    ys[t + 256] = (ga[t + 256] * d1) / den + gb[t + 256];
    ys[t + 512] = (ga[t + 512] * d2) / den + gb[t + 512];
    __syncthreads();
    int c = blockIdx.x * 128 + (t & 31) * 4;
    int kq = t >> 5;
    float4 acc = {0.f, 0.f, 0.f, 0.f};
#pragma unroll 8
    for (int i = 0; i < 96; ++i) {
        int k = kq * 96 + i;
        float4 w = *(const float4*)&W1[(size_t)k * 3072 + c];
        float y = ys[k];
        acc.x = fmaf(y, w.x, acc.x); acc.y = fmaf(y, w.y, acc.y);
        acc.z = fmaf(y, w.z, acc.z); acc.w = fmaf(y, w.w, acc.w);
    }
    part[kq][t & 31] = acc;
    __syncthreads();
    if (t < 32) {
        float4 s = {0.f, 0.f, 0.f, 0.f};
#pragma unroll
        for (int i = 0; i < 8; ++i) {
            float4 v = part[i][t];
            s.x += v.x; s.y += v.y; s.z += v.z; s.w += v.w;
        }
        int cc = blockIdx.x * 128 + t * 4;
        float4 b4 = *(const float4*)&b1[cc];
        float* o = f1w + (size_t)b * 3072 + cc;
        o[0] = fmaxf(s.x + b4.x, 0.f); o[1] = fmaxf(s.y + b4.y, 0.f);
        o[2] = fmaxf(s.z + b4.z, 0.f); o[3] = fmaxf(s.w + b4.w, 0.f);
    }
}

// ---------------------------------------------------------------------------
// x3 = x2 + f1 @ W2 + b2. grid (12, 8). Tail-free.
__global__ __launch_bounds__(256) void x3_k(
    const float* __restrict__ f1w, const float* __restrict__ W2,
    const float* __restrict__ b2, const float* __restrict__ x2w,
    float* __restrict__ x3w)
{
    __shared__ float ys[3072];
    __shared__ float4 part[16][17];
    int b = blockIdx.y, t = threadIdx.x;
    const float* xr = f1w + (size_t)b * 3072;
    for (int i = t; i < 3072; i += 256) ys[i] = xr[i];
    __syncthreads();
    int c = blockIdx.x * 64 + (t & 15) * 4;
    int kq = t >> 4;
    float4 acc = {0.f, 0.f, 0.f, 0.f};
#pragma unroll 8
    for (int i = 0; i < 192; ++i) {
        int k = kq * 192 + i;
        float4 w = *(const float4*)&W2[(size_t)k * 768 + c];
        float y = ys[k];
        acc.x = fmaf(y, w.x, acc.x); acc.y = fmaf(y, w.y, acc.y);
        acc.z = fmaf(y, w.z, acc.z); acc.w = fmaf(y, w.w, acc.w);
    }
    part[kq][t & 15] = acc;
    __syncthreads();
    if (t < 16) {
        float4 s = {0.f, 0.f, 0.f, 0.f};
#pragma unroll
        for (int i = 0; i < 16; ++i) {
            float4 v = part[i][t];
            s.x += v.x; s.y += v.y; s.z += v.z; s.w += v.w;
        }
        int cc = blockIdx.x * 64 + t * 4;
        float4 b4 = *(const float4*)&b2[cc];
        const float* x2r = x2w + (size_t)b * 768 + cc;
        float* o = x3w + (size_t)b * 768 + cc;
        o[0] = x2r[0] + s.x + b4.x; o[1] = x2r[1] + s.y + b4.y;
        o[2] = x2r[2] + s.z + b4.z; o[3] = x2r[3] + s.w + b4.w;
    }
}

// ---------------------------------------------------------------------------
// Head logits, k-split (grid 8 kg x 8 b), LNf fused, double partials.
// LAST block per batch (atomic counter, no spinning) sums the 8 partials,
// writes class logits + entropy -> kk, and ranks the POOL LOGITS directly
// (top_k(softmax(z)) == top_k(z): exp monotonic, uniform Z).
__global__ __launch_bounds__(256) void logits_part(
    const float* __restrict__ x3w, const float* __restrict__ ga,
    const float* __restrict__ gb, const float* __restrict__ Wpool,
    const float* __restrict__ Wcls, double* __restrict__ lp,
    const float* __restrict__ bpool, const float* __restrict__ bcls,
    float* __restrict__ out, int* __restrict__ topw, int* __restrict__ kkw,
    int* __restrict__ cnts)
{
    __shared__ float ys[768];
    __shared__ float red[4];
    __shared__ double sPd[100];
    __shared__ double sC7d[7];
    __shared__ int sOld;
    int kg = blockIdx.x, b = blockIdx.y, t = threadIdx.x;
    const float* xr = x3w + (size_t)b * 768;
    float a0 = xr[t], a1 = xr[t + 256], a2 = xr[t + 512];
    float mean = bsum256(a0 + a1 + a2, red) * (1.0f / 768.0f);
    float d0 = a0 - mean, d1 = a1 - mean, d2 = a2 - mean;
    float var = bsum256(d0 * d0 + d1 * d1 + d2 * d2, red) * (1.0f / 767.0f);
    float den = sqrtf(var) + 1e-6f;
    ys[t]       = (ga[t] * d0) / den + gb[t];
    ys[t + 256] = (ga[t + 256] * d1) / den + gb[t + 256];
    ys[t + 512] = (ga[t + 512] * d2) / den + gb[t + 512];
    __syncthreads();
    int kbase = kg * 96;
    if (t < 100) {
        double a = 0.0;
#pragma unroll 8
        for (int i = 0; i < 96; ++i) {
            int k = kbase + i;
            a = fma((double)ys[k], (double)Wpool[k * 100 + t], a);
        }
        lp[((size_t)b * 8 + kg) * 112 + t] = a;
    } else if (t < 107) {
        int c = t - 100;
        double a = 0.0;
#pragma unroll 8
        for (int i = 0; i < 96; ++i) {
            int k = kbase + i;
            a = fma((double)ys[k], (double)Wcls[k * 7 + c], a);
        }
        lp[((size_t)b * 8 + kg) * 112 + t] = a;
    }

    // ---- last-block decide (one atomic per block; non-last blocks exit) ----
    __syncthreads();     // drain this block's lp stores
    __threadfence();
    if (t == 0)
        sOld = __hip_atomic_fetch_add(&cnts[b], 1, __ATOMIC_ACQ_REL,
                                      __HIP_MEMORY_SCOPE_AGENT);
    __syncthreads();
    if (sOld != 7) return;

    if (t < 107) {
        double a = (t < 100) ? (double)bpool[t] : (double)bcls[t - 100];
#pragma unroll
        for (int g = 0; g < 8; ++g) a += lp[((size_t)b * 8 + g) * 112 + t];
        if (t < 100) sPd[t] = a;
        else {
            sC7d[t - 100] = a;
            out[OUT_CLS_OFF + b * 7 + (t - 100)] = (float)a;
        }
    }
    __syncthreads();
    if (t == 0) {
        double m7 = sC7d[0];
        for (int j = 1; j < 7; ++j) m7 = fmax(m7, sC7d[j]);
        double es[7]; double z = 0.0;
        for (int j = 0; j < 7; ++j) { es[j] = exp(sC7d[j] - m7); z += es[j]; }
        double ent = 0.0;
        for (int j = 0; j < 7; ++j) { double pr = es[j] / z; ent -= pr * log(pr + 1e-9); }
        double ne = ent / log(7.0);
        int kk = (int)floor(1.0 + ne * 99.0);
        kkw[b] = kk < 1 ? 1 : (kk > 100 ? 100 : kk);
    }
    if (t < 100) {
        double pi = sPd[t];     // rank on logits: same order as probabilities
        int r = 0;
#pragma unroll 4
        for (int j = 0; j < 100; ++j) {
            double pj = sPd[j];
            r += (pj > pi) || (pj == pi && j < t);
        }
        topw[b * 100 + r] = t;  // descending, stable (lower index first)
    }
}

// ---------------------------------------------------------------------------
// gather: out[b, r, :] = (r < kk[b]) ? pool[top[b][r], :] : 0. grid (100, 8).
__global__ __launch_bounds__(192) void gather_k(
    const float* __restrict__ pool, const int* __restrict__ topw,
    const int* __restrict__ kkw, float* __restrict__ out)
{
    int r = blockIdx.x, b = blockIdx.y, t = threadIdx.x;
    int idx = topw[b * 100 + r];
    bool keep = r < kkw[b];
    const float4* src = (const float4*)(pool + (size_t)idx * 768);
    float4* dst = (float4*)(out + (size_t)b * 76800 + (size_t)r * 768);
    float4 z = {0.f, 0.f, 0.f, 0.f};
    dst[t] = keep ? src[t] : z;
}

// ---------------------------------------------------------------------------
extern "C" void kernel_launch(void* const* d_in, const int* in_sizes, int n_in,
                              void* d_out, int out_size, void* d_ws, size_t ws_size,
                              hipStream_t stream) {
    (void)in_sizes; (void)n_in; (void)out_size; (void)ws_size;
    const float* tf    = (const float*)d_in[0];
    const float* pool  = (const float*)d_in[1];
    const float* clsT  = (const float*)d_in[2];
    const float* Wq    = (const float*)d_in[3];
    const float* bq    = (const float*)d_in[4];
    const float* Wk    = (const float*)d_in[5];
    const float* bk    = (const float*)d_in[6];
    const float* Wv    = (const float*)d_in[7];
    const float* bv    = (const float*)d_in[8];
    const float* Wo    = (const float*)d_in[9];
    const float* bo    = (const float*)d_in[10];
    const float* ln1a  = (const float*)d_in[11];
    const float* ln1b  = (const float*)d_in[12];
    const float* ln2a  = (const float*)d_in[13];
    const float* ln2b  = (const float*)d_in[14];
    const float* W1    = (const float*)d_in[15];
    const float* b1    = (const float*)d_in[16];
    const float* W2    = (const float*)d_in[17];
    const float* b2    = (const float*)d_in[18];
    const float* lnfa  = (const float*)d_in[19];
    const float* lnfb  = (const float*)d_in[20];
    const float* Wpool = (const float*)d_in[21];
    const float* bpool = (const float*)d_in[22];
    const float* Wcls  = (const float*)d_in[23];
    const float* bcls  = (const float*)d_in[24];
    float* out = (float*)d_out;
    char* ws = (char*)d_ws;

    float*  wkqc  = (float*)(ws + 0);           // 49,408
    float*  q0    = (float*)(ws + 49408);       // 3,072
    float*  colw  = (float*)(ws + 52480);       // 6,144
    float*  up    = (float*)(ws + 58624);       // 25,165,824 (8 x 64 x 16 x 768)
    float*  upz   = (float*)(ws + 25224448);    // 32,768
    float*  upc1  = (float*)(ws + 25257216);    // 32,768
    float*  o0    = (float*)(ws + 25289984);    // 24,576
    float*  x2w   = (float*)(ws + 25314560);    // 24,576
    float*  f1w   = (float*)(ws + 25339136);    // 98,304
    float*  x3w   = (float*)(ws + 25437440);    // 24,576
    int*    topw  = (int*)(ws + 25462016);      // 3,200
    int*    kkw   = (int*)(ws + 25465216);      // 32
    double* lp    = (double*)(ws + 25465248);   // 57,344 (8-aligned)
    int*    cnts  = (int*)(ws + 25522592);      // 64   (total ~25.5 MB)

    prep_a<<<24, 256, 0, stream>>>(clsT, ln1a, ln1b, Wq, bq, Wk, q0, colw, cnts);
    prep_b<<<48, 256, 0, stream>>>(Wk, bk, q0, colw, wkqc);
    score_upart<<<512, 256, 0, stream>>>(tf, clsT, ln1a, wkqc, up, upz, upc1);
    o0_k<<<dim3(16, 8), 256, 0, stream>>>(up, upz, upc1, ln1a, ln1b, Wv, bv, o0);
    x2_k<<<dim3(12, 8), 256, 0, stream>>>(o0, Wo, bo, clsT, x2w);
    f1_k<<<dim3(24, 8), 256, 0, stream>>>(x2w, ln2a, ln2b, W1, b1, f1w);
    x3_k<<<dim3(12, 8), 256, 0, stream>>>(f1w, W2, b2, x2w, x3w);
    logits_part<<<dim3(8, 8), 256, 0, stream>>>(x3w, lnfa, lnfb, Wpool, Wcls,
                                                lp, bpool, bcls, out, topw,
                                                kkw, cnts);
    gather_k<<<dim3(100, 8), 192, 0, stream>>>(pool, topw, kkw, out);
}